// Round 8
// baseline (402.544 us; speedup 1.0000x reference)
//
#include <hip/hip_runtime.h>
#include <hip/hip_bf16.h>

#define NPATCH 15376       // 124*124 patches
#define NP     15488       // B rows padded: 121*128
#define NT     121         // B col-tiles (128 each)
#define ATILES 128         // A rows padded: 128*128 = 16384
#define TILE_SHORTS 12288  // 12*128*8 shorts per 128-row tile (24KB)
#define EPSA   2.0f        // acc-space flag margin (== 4.0 in dist-space, validated r4-r7)
#define PMW    124         // PM row stride (121 used)

typedef __attribute__((ext_vector_type(8))) __bf16 bf16x8;
typedef __attribute__((ext_vector_type(4))) float  f32x4;

__device__ __forceinline__ void gload_lds16(const void* g, void* l) {
    __builtin_amdgcn_global_load_lds((const __attribute__((address_space(1))) unsigned int*)g,
                                     (__attribute__((address_space(3))) unsigned int*)l, 16, 0, 0);
}
__device__ __forceinline__ unsigned short f2bf(float x) {
    __hip_bfloat16 h = __float2bfloat16(x);
    return *(unsigned short*)&h;
}
__device__ __forceinline__ float bf2f(unsigned short u) {
    __hip_bfloat16 h; *(unsigned short*)&h = u;
    return __bfloat162float(h);
}
template<int CTRL>
__device__ __forceinline__ float dppmax(float x) {
    int xi = __builtin_bit_cast(int, x);
    int yi = __builtin_amdgcn_update_dpp(xi, xi, CTRL, 0xf, 0xf, true);
    return fmaxf(x, __builtin_bit_cast(float, yi));
}

// ---------- fused squared norms: Y2 (padded, 3e38 pads) and X2
__device__ __forceinline__ float patch_sq(const float* __restrict__ img, int p) {
    int pr = p / 124, pc = p - pr * 124;
    const float* base = img + pr * 128 + pc;
    float s = 0.f;
    #pragma unroll
    for (int ch = 0; ch < 3; ++ch)
        #pragma unroll
        for (int di = 0; di < 5; ++di)
            #pragma unroll
            for (int dj = 0; dj < 5; ++dj) {
                float v = base[ch * 16384 + di * 128 + dj];
                s = fmaf(v, v, s);
            }
    return s;
}
__global__ void sqnorm2(const float* __restrict__ crop, const float* __restrict__ orig,
                        float* __restrict__ X2, float* __restrict__ Y2) {
    int p = blockIdx.x * 256 + threadIdx.x;
    if (p < NP) {
        Y2[p] = (p < NPATCH) ? patch_sq(orig, p) : 3.0e38f;
    } else {
        int q = p - NP;
        if (q < NPATCH) X2[q] = patch_sq(crop, q);
    }
}

// ---------- pack both matrices: tile-major [tile][kslot12][row128][8] bf16.
// features 0..74 = bf16(patch); slot 75/76: A -> -0.5,-0.5 ; B -> Y2hi,Y2lo; 77..95 = 0.
__global__ void pack2(const float* __restrict__ crop, const float* __restrict__ orig,
                      unsigned short* __restrict__ Abig, unsigned short* __restrict__ Bbig,
                      const float* __restrict__ Y2) {
    int cid = blockIdx.x * 256 + threadIdx.x;     // 0 .. 128*1536 + 121*1536 - 1
    const float* img;
    unsigned short* dst;
    bool isA;
    if (cid < ATILES * 1536) { img = crop; dst = Abig; isA = true; }
    else { cid -= ATILES * 1536; img = orig; dst = Bbig; isA = false; }
    int t = cid / 1536, rem = cid - t * 1536;
    int s = rem >> 7, r = rem & 127;
    int row = t * 128 + r;
    unsigned short ch8[8];
    #pragma unroll
    for (int e = 0; e < 8; ++e) {
        int k = s * 8 + e;
        unsigned short v = 0;
        if (k < 75) {
            if (row < NPATCH) {
                int c = k / 25, rem2 = k - c * 25;
                int di = rem2 / 5, dj = rem2 - di * 5;
                int pr = row / 124, pc = row - pr * 124;
                v = f2bf(img[c * 16384 + (pr + di) * 128 + (pc + dj)]);
            }
        } else if (k < 77) {
            if (isA) v = f2bf(-0.5f);
            else {
                float yv = Y2[row];               // row < 15488
                unsigned short hi = f2bf(yv);
                v = (k == 75) ? hi : f2bf(yv - bf2f(hi));
            }
        }
        ch8[e] = v;
    }
    *(ulonglong2*)(dst + (size_t)cid * 8) = *(ulonglong2*)ch8;
}

// ---------- persistent-chunk MFMA screen: PM[row][tile] = max_cols(acc), acc = dot - Y2/2
__global__ __launch_bounds__(512, 2)
void dist_mfma3(const unsigned short* __restrict__ A, const unsigned short* __restrict__ B,
                float* __restrict__ PM) {
    __shared__ __align__(16) unsigned short Bs[2][12][128][8];  // 48 KB
    __shared__ __align__(16) float Red[2][512];                 // 4 KB

    const int tid = threadIdx.x, lane = tid & 63, wid = tid >> 6;
    const int rg = wid >> 1, cg = wid & 1;
    const int l15 = lane & 15, l4 = lane >> 4;
    const int chunk = blockIdx.x & 7, rowblk = blockIdx.x >> 3;   // chunk per XCD
    const int t0 = chunk * 15 + (chunk ? 1 : 0);
    const int nt = chunk ? 15 : 16;                               // 16+15*7 = 121
    const int rowbase = rowblk * 512;

#define STAGE(buf, tile)                                                          \
    {                                                                             \
        const char* _g = (const char*)(B + (size_t)(tile) * TILE_SHORTS);         \
        char* _l = (char*)&Bs[buf][0][0][0];                                      \
        _Pragma("unroll")                                                         \
        for (int _i = 0; _i < 3; ++_i)                                            \
            gload_lds16(_g + (tid + _i * 512) * 16, _l + (tid + _i * 512) * 16);  \
    }

    STAGE(0, t0);

    // A fragments: 24 bf16x8 (96 VGPR), direct global, one-time.
    bf16x8 a[8][3];
    {
        const unsigned short* Abase =
            A + ((size_t)(rowblk * 4 + rg) * 12 + l4) * 1024 + (size_t)l15 * 8;
        #pragma unroll
        for (int mi = 0; mi < 8; ++mi)
            #pragma unroll
            for (int ks = 0; ks < 3; ++ks)
                a[mi][ks] = *(const bf16x8*)(Abase + ks * 4096 + mi * 128);
    }

    asm volatile("s_waitcnt vmcnt(0)" ::: "memory");
    __syncthreads();

    int cur = 0;
    for (int it = 0; it < nt; ++it) {
        if (it + 1 < nt) STAGE(cur ^ 1, t0 + it + 1);

        f32x4 acc[8][4];
        #pragma unroll
        for (int ks = 0; ks < 3; ++ks) {
            bf16x8 b[4];
            #pragma unroll
            for (int ni = 0; ni < 4; ++ni)
                b[ni] = *(const bf16x8*)&Bs[cur][ks * 4 + l4][cg * 64 + ni * 16 + l15][0];
            #pragma unroll
            for (int mi = 0; mi < 8; ++mi)
                #pragma unroll
                for (int ni = 0; ni < 4; ++ni)
                    acc[mi][ni] = __builtin_amdgcn_mfma_f32_16x16x32_bf16(
                        a[mi][ks], b[ni],
                        (ks == 0) ? (f32x4){0.f, 0.f, 0.f, 0.f} : acc[mi][ni], 0, 0, 0);
        }

        // per-row max over this wave's 64 cols: ni-fold + 4 DPP-max (16-lane groups)
        #pragma unroll
        for (int mi = 0; mi < 8; ++mi) {
            f32x4 m4;
            #pragma unroll
            for (int j = 0; j < 4; ++j) {
                float m = fmaxf(fmaxf(acc[mi][0][j], acc[mi][1][j]),
                                fmaxf(acc[mi][2][j], acc[mi][3][j]));
                m = dppmax<0xB1>(m);    // quad_perm xor1
                m = dppmax<0x4E>(m);    // quad_perm xor2
                m = dppmax<0x141>(m);   // row_half_mirror
                m = dppmax<0x140>(m);   // row_mirror
                m4[j] = m;
            }
            if (l15 == 0)
                *(f32x4*)&Red[cg][rg * 128 + mi * 16 + l4 * 4] = m4;
        }
        __syncthreads();
        {   // combine cg halves, store PM[row][tile]
            float v = fmaxf(Red[0][tid], Red[1][tid]);
            int grow = rowbase + tid;
            if (grow < NPATCH) PM[(size_t)grow * PMW + t0 + it] = v;
        }
        asm volatile("s_waitcnt vmcnt(0)" ::: "memory");
        __syncthreads();
        cur ^= 1;
    }
#undef STAGE
}

// ---------- repair: one WAVE per row; coalesced PM read; no block-wide reduces
__global__ __launch_bounds__(256)
void repair_kernel(const float* __restrict__ crop, const float* __restrict__ orig,
                   const float* __restrict__ X2, const float* __restrict__ Y2,
                   const float* __restrict__ PM,
                   float* __restrict__ out, float* __restrict__ rsum) {
    __shared__ float xs[4][76];
    const int tid = threadIdx.x, lane = tid & 63, w = tid >> 6;
    const int rbase = blockIdx.x * 4;

    // stage the 4 rows' x-patches (300 scattered floats, one barrier total)
    for (int t = tid; t < 300; t += 256) {
        int w2 = t / 75, k = t - w2 * 75;
        int rr = rbase + w2;
        int ch = k / 25, rem = k % 25, di = rem / 5, dj = rem % 5;
        int pr = rr / 124, pc = rr - pr * 124;
        xs[w2][k] = crop[ch * 16384 + (pr + di) * 128 + (pc + dj)];
    }
    __syncthreads();

    const int r = rbase + w;                        // < NPATCH always (3844*4)
    float pm0 = PM[(size_t)r * PMW + lane];
    float pm1 = (lane < NT - 64) ? PM[(size_t)r * PMW + 64 + lane] : -3.4e38f;
    float mt = fmaxf(pm0, pm1);
    #pragma unroll
    for (int off = 1; off < 64; off <<= 1)
        mt = fmaxf(mt, __shfl_xor(mt, off));
    unsigned long long m0 = __ballot(pm0 >= mt - EPSA);
    unsigned long long m1 = __ballot((lane < NT - 64) && pm1 >= mt - EPSA);

    const float x2 = X2[r];
    float bd0 = 3.4e38f, bd1 = 3.4e38f;
    int   bi0 = 0x7fffffff, bi1 = 0x7fffffff;

    #pragma unroll
    for (int half = 0; half < 2; ++half) {
        unsigned long long mask = half ? m1 : m0;
        const int toff = half * 64;
        while (mask) {
            int ct = (__ffsll(mask) - 1) + toff;
            mask &= mask - 1;
            const int jb = ct * 128 + lane;
            // two columns per lane, independent accumulators (ILP)
            int j0 = jb, j1 = jb + 64;
            bool v0 = j0 < NPATCH, v1 = j1 < NPATCH;
            int jr0 = j0 / 124, jc0 = j0 - jr0 * 124;
            int jr1 = j1 / 124, jc1 = j1 - jr1 * 124;
            const float* yb0 = orig + jr0 * 128 + jc0;
            const float* yb1 = orig + jr1 * 128 + jc1;
            float dot0 = 0.f, dot1 = 0.f;
            #pragma unroll
            for (int ch = 0; ch < 3; ++ch)
                #pragma unroll
                for (int di = 0; di < 5; ++di)
                    #pragma unroll
                    for (int dj = 0; dj < 5; ++dj) {
                        float xv = xs[w][ch * 25 + di * 5 + dj];
                        if (v0) dot0 = fmaf(xv, yb0[ch * 16384 + di * 128 + dj], dot0);
                        if (v1) dot1 = fmaf(xv, yb1[ch * 16384 + di * 128 + dj], dot1);
                    }
            if (v0) {
                float d = fmaf(-2.f, dot0, x2) + Y2[j0];
                if (d < bd0 || (d == bd0 && j0 < bi0)) { bd0 = d; bi0 = j0; }
            }
            if (v1) {
                float d = fmaf(-2.f, dot1, x2) + Y2[j1];
                if (d < bd1 || (d == bd1 && j1 < bi1)) { bd1 = d; bi1 = j1; }
            }
        }
    }
    if (bd1 < bd0 || (bd1 == bd0 && bi1 < bi0)) { bd0 = bd1; bi0 = bi1; }
    #pragma unroll
    for (int off = 1; off < 64; off <<= 1) {
        float od = __shfl_xor(bd0, off);
        int   oi = __shfl_xor(bi0, off);
        if (od < bd0 || (od == bd0 && oi < bi0)) { bd0 = od; bi0 = oi; }
    }
    if (lane == 0) {
        out[1 + r] = (float)bi0;
        rsum[r] = bd0;
    }
}

// ---------- deterministic final loss
__global__ void loss_final(const float* __restrict__ rsum, float* __restrict__ out) {
    __shared__ float s[256];
    float acc = 0.f;
    for (int i = threadIdx.x; i < NPATCH; i += 256) acc += rsum[i];
    s[threadIdx.x] = acc;
    __syncthreads();
    for (int st = 128; st > 0; st >>= 1) {
        if (threadIdx.x < st) s[threadIdx.x] += s[threadIdx.x + st];
        __syncthreads();
    }
    if (threadIdx.x == 0) out[0] = s[0] / (float)NPATCH;
}

extern "C" void kernel_launch(void* const* d_in, const int* in_sizes, int n_in,
                              void* d_out, int out_size, void* d_ws, size_t ws_size,
                              hipStream_t stream) {
    const float* crop = (const float*)d_in[0];
    const float* orig = (const float*)d_in[1];
    float* out = (float*)d_out;

    unsigned short* Abig = (unsigned short*)d_ws;               // 128*12288 shorts
    unsigned short* Bbig = Abig + (size_t)ATILES * TILE_SHORTS; // 121*12288 shorts
    float* X2 = (float*)(Bbig + (size_t)NT * TILE_SHORTS);      // NPATCH
    float* Y2 = X2 + NPATCH;                                    // NP (pads 3e38)
    float* PM = Y2 + NP;                                        // NPATCH*124
    float* RS = PM + (size_t)NPATCH * PMW;                      // NPATCH

    sqnorm2<<<(NP + NPATCH + 255) / 256, 256, 0, stream>>>(crop, orig, X2, Y2);
    pack2<<<(ATILES + NT) * 6, 256, 0, stream>>>(crop, orig, Abig, Bbig, Y2);
    dist_mfma3<<<256, 512, 0, stream>>>(Abig, Bbig, PM);
    repair_kernel<<<NPATCH / 4, 256, 0, stream>>>(crop, orig, X2, Y2, PM, out, RS);
    loss_final<<<1, 256, 0, stream>>>(RS, out);
}

// Round 9
// 376.518 us; speedup vs baseline: 1.0691x; 1.0691x over previous
//
#include <hip/hip_runtime.h>
#include <hip/hip_bf16.h>

#define NPATCH 15376       // 124*124 patches
#define NP     15488       // B rows padded: 121*128
#define NT     121         // B col-tiles (128 each)
#define ATILES 128         // A rows padded: 128*128 = 16384
#define TILE_SHORTS 12288  // 12*128*8 shorts per 128-row tile (24KB)
#define EPSA   2.0f        // acc-space flag margin (== 4.0 in dist-space, validated r4-r8)
#define PMW    124         // PM row stride (121 used)

typedef __attribute__((ext_vector_type(8))) __bf16 bf16x8;
typedef __attribute__((ext_vector_type(4))) float  f32x4;

__device__ __forceinline__ void gload_lds16(const void* g, void* l) {
    __builtin_amdgcn_global_load_lds((const __attribute__((address_space(1))) unsigned int*)g,
                                     (__attribute__((address_space(3))) unsigned int*)l, 16, 0, 0);
}
__device__ __forceinline__ unsigned short f2bf(float x) {
    __hip_bfloat16 h = __float2bfloat16(x);
    return *(unsigned short*)&h;
}
__device__ __forceinline__ float bf2f(unsigned short u) {
    __hip_bfloat16 h; *(unsigned short*)&h = u;
    return __bfloat162float(h);
}
template<int CTRL>
__device__ __forceinline__ float dppmax(float x) {
    int xi = __builtin_bit_cast(int, x);
    int yi = __builtin_amdgcn_update_dpp(xi, xi, CTRL, 0xf, 0xf, true);
    return fmaxf(x, __builtin_bit_cast(float, yi));
}
__device__ __forceinline__ unsigned int fsort(float d) {   // monotone float->uint
    unsigned int b = __builtin_bit_cast(unsigned int, d);
    return (b & 0x80000000u) ? ~b : (b | 0x80000000u);
}

// ---------- fused squared norms (+ worklist counter reset)
__device__ __forceinline__ float patch_sq(const float* __restrict__ img, int p) {
    int pr = p / 124, pc = p - pr * 124;
    const float* base = img + pr * 128 + pc;
    float s = 0.f;
    #pragma unroll
    for (int ch = 0; ch < 3; ++ch)
        #pragma unroll
        for (int di = 0; di < 5; ++di)
            #pragma unroll
            for (int dj = 0; dj < 5; ++dj) {
                float v = base[ch * 16384 + di * 128 + dj];
                s = fmaf(v, v, s);
            }
    return s;
}
__global__ void sqnorm2(const float* __restrict__ crop, const float* __restrict__ orig,
                        float* __restrict__ X2, float* __restrict__ Y2,
                        unsigned int* __restrict__ WLn) {
    int p = blockIdx.x * 256 + threadIdx.x;
    if (p == 0) *WLn = 0;
    if (p < NP) {
        Y2[p] = (p < NPATCH) ? patch_sq(orig, p) : 3.0e38f;
    } else {
        int q = p - NP;
        if (q < NPATCH) X2[q] = patch_sq(crop, q);
    }
}

// ---------- pack both matrices: tile-major [tile][kslot12][row128][8] bf16.
__global__ void pack2(const float* __restrict__ crop, const float* __restrict__ orig,
                      unsigned short* __restrict__ Abig, unsigned short* __restrict__ Bbig,
                      const float* __restrict__ Y2) {
    int cid = blockIdx.x * 256 + threadIdx.x;
    const float* img;
    unsigned short* dst;
    bool isA;
    if (cid < ATILES * 1536) { img = crop; dst = Abig; isA = true; }
    else { cid -= ATILES * 1536; img = orig; dst = Bbig; isA = false; }
    int t = cid / 1536, rem = cid - t * 1536;
    int s = rem >> 7, r = rem & 127;
    int row = t * 128 + r;
    unsigned short ch8[8];
    #pragma unroll
    for (int e = 0; e < 8; ++e) {
        int k = s * 8 + e;
        unsigned short v = 0;
        if (k < 75) {
            if (row < NPATCH) {
                int c = k / 25, rem2 = k - c * 25;
                int di = rem2 / 5, dj = rem2 - di * 5;
                int pr = row / 124, pc = row - pr * 124;
                v = f2bf(img[c * 16384 + (pr + di) * 128 + (pc + dj)]);
            }
        } else if (k < 77) {
            if (isA) v = f2bf(-0.5f);
            else {
                float yv = Y2[row];
                unsigned short hi = f2bf(yv);
                v = (k == 75) ? hi : f2bf(yv - bf2f(hi));
            }
        }
        ch8[e] = v;
    }
    *(ulonglong2*)(dst + (size_t)cid * 8) = *(ulonglong2*)ch8;
}

// ---------- persistent-chunk MFMA screen: PM[row][tile] = max_cols(dot - Y2/2)
__global__ __launch_bounds__(512, 2)
void dist_mfma3(const unsigned short* __restrict__ A, const unsigned short* __restrict__ B,
                float* __restrict__ PM) {
    __shared__ __align__(16) unsigned short Bs[2][12][128][8];  // 48 KB
    __shared__ __align__(16) float Red[2][512];                 // 4 KB

    const int tid = threadIdx.x, lane = tid & 63, wid = tid >> 6;
    const int rg = wid >> 1, cg = wid & 1;
    const int l15 = lane & 15, l4 = lane >> 4;
    const int chunk = blockIdx.x & 7, rowblk = blockIdx.x >> 3;
    const int t0 = chunk * 15 + (chunk ? 1 : 0);
    const int nt = chunk ? 15 : 16;
    const int rowbase = rowblk * 512;

#define STAGE(buf, tile)                                                          \
    {                                                                             \
        const char* _g = (const char*)(B + (size_t)(tile) * TILE_SHORTS);         \
        char* _l = (char*)&Bs[buf][0][0][0];                                      \
        _Pragma("unroll")                                                         \
        for (int _i = 0; _i < 3; ++_i)                                            \
            gload_lds16(_g + (tid + _i * 512) * 16, _l + (tid + _i * 512) * 16);  \
    }

    STAGE(0, t0);

    bf16x8 a[8][3];
    {
        const unsigned short* Abase =
            A + ((size_t)(rowblk * 4 + rg) * 12 + l4) * 1024 + (size_t)l15 * 8;
        #pragma unroll
        for (int mi = 0; mi < 8; ++mi)
            #pragma unroll
            for (int ks = 0; ks < 3; ++ks)
                a[mi][ks] = *(const bf16x8*)(Abase + ks * 4096 + mi * 128);
    }

    asm volatile("s_waitcnt vmcnt(0)" ::: "memory");
    __syncthreads();

    int cur = 0;
    for (int it = 0; it < nt; ++it) {
        if (it + 1 < nt) STAGE(cur ^ 1, t0 + it + 1);

        f32x4 acc[8][4];
        #pragma unroll
        for (int ks = 0; ks < 3; ++ks) {
            bf16x8 b[4];
            #pragma unroll
            for (int ni = 0; ni < 4; ++ni)
                b[ni] = *(const bf16x8*)&Bs[cur][ks * 4 + l4][cg * 64 + ni * 16 + l15][0];
            #pragma unroll
            for (int mi = 0; mi < 8; ++mi)
                #pragma unroll
                for (int ni = 0; ni < 4; ++ni)
                    acc[mi][ni] = __builtin_amdgcn_mfma_f32_16x16x32_bf16(
                        a[mi][ks], b[ni],
                        (ks == 0) ? (f32x4){0.f, 0.f, 0.f, 0.f} : acc[mi][ni], 0, 0, 0);
        }

        #pragma unroll
        for (int mi = 0; mi < 8; ++mi) {
            f32x4 m4;
            #pragma unroll
            for (int j = 0; j < 4; ++j) {
                float m = fmaxf(fmaxf(acc[mi][0][j], acc[mi][1][j]),
                                fmaxf(acc[mi][2][j], acc[mi][3][j]));
                m = dppmax<0xB1>(m);
                m = dppmax<0x4E>(m);
                m = dppmax<0x141>(m);
                m = dppmax<0x140>(m);
                m4[j] = m;
            }
            if (l15 == 0)
                *(f32x4*)&Red[cg][rg * 128 + mi * 16 + l4 * 4] = m4;
        }
        __syncthreads();
        {
            float v = fmaxf(Red[0][tid], Red[1][tid]);
            int grow = rowbase + tid;
            if (grow < NPATCH) PM[(size_t)grow * PMW + t0 + it] = v;
        }
        asm volatile("s_waitcnt vmcnt(0)" ::: "memory");
        __syncthreads();
        cur ^= 1;
    }
#undef STAGE
}

// ---------- flag: wave per row, no barriers; push (row,tile) items to worklist
__global__ __launch_bounds__(256)
void flag_kernel(const float* __restrict__ PM,
                 unsigned int* __restrict__ WL, unsigned int* __restrict__ WLn,
                 unsigned long long* __restrict__ RES) {
    const int tid = threadIdx.x, lane = tid & 63, w = tid >> 6;
    const int r = blockIdx.x * 4 + w;                     // < NPATCH (3844*4)

    float pm0 = PM[(size_t)r * PMW + lane];
    float pm1 = (lane < NT - 64) ? PM[(size_t)r * PMW + 64 + lane] : -3.4e38f;
    float mt = fmaxf(pm0, pm1);
    #pragma unroll
    for (int off = 1; off < 64; off <<= 1)
        mt = fmaxf(mt, __shfl_xor(mt, off));
    unsigned long long m0 = __ballot(pm0 >= mt - EPSA);
    unsigned long long m1 = __ballot((lane < NT - 64) && pm1 >= mt - EPSA);

    if (lane == 0) RES[r] = 0xFFFFFFFFFFFFFFFFULL;

    int n0 = __popcll(m0);
    unsigned int base = 0;
    if (lane == 0) base = atomicAdd(WLn, (unsigned int)(n0 + __popcll(m1)));
    base = __shfl(base, 0);
    unsigned long long below = (lane == 0) ? 0ULL : (~0ULL >> (64 - lane));
    if ((m0 >> lane) & 1) WL[base + __popcll(m0 & below)] = ((unsigned)r << 7) | lane;
    if ((m1 >> lane) & 1) WL[base + n0 + __popcll(m1 & below)] = ((unsigned)r << 7) | (lane + 64);
}

// ---------- repair items: grid-stride waves; one (row,tile) per wave; atomicMin combine
__global__ __launch_bounds__(256)
void repair_items(const float* __restrict__ crop, const float* __restrict__ orig,
                  const float* __restrict__ X2, const float* __restrict__ Y2,
                  const unsigned int* __restrict__ WL, const unsigned int* __restrict__ WLn,
                  unsigned long long* __restrict__ RES) {
    const int lane = threadIdx.x & 63;
    const unsigned int gw = (blockIdx.x * 256 + threadIdx.x) >> 6;
    const unsigned int nw = (gridDim.x * 256) >> 6;
    const unsigned int n = *WLn;

    for (unsigned int i = gw; i < n; i += nw) {
        unsigned int item = WL[i];
        int r = item >> 7, tile = item & 127;
        int pr = r / 124, pc = r - pr * 124;
        const float* xb = crop + pr * 128 + pc;
        float x2 = X2[r];

        int j0 = tile * 128 + lane, j1 = j0 + 64;
        bool v0 = j0 < NPATCH, v1 = j1 < NPATCH;
        int jr0 = j0 / 124, jc0 = j0 - jr0 * 124;
        int jr1 = j1 / 124, jc1 = j1 - jr1 * 124;
        const float* yb0 = orig + jr0 * 128 + jc0;
        const float* yb1 = orig + jr1 * 128 + jc1;
        float dot0 = 0.f, dot1 = 0.f;
        #pragma unroll
        for (int ch = 0; ch < 3; ++ch)
            #pragma unroll
            for (int di = 0; di < 5; ++di)
                #pragma unroll
                for (int dj = 0; dj < 5; ++dj) {
                    float xv = xb[ch * 16384 + di * 128 + dj];   // wave-uniform
                    dot0 = fmaf(xv, yb0[ch * 16384 + di * 128 + dj], dot0);
                    dot1 = fmaf(xv, yb1[ch * 16384 + di * 128 + dj], dot1);
                }
        float d0 = fmaf(-2.f, dot0, x2) + Y2[j0];
        float d1 = fmaf(-2.f, dot1, x2) + Y2[j1];
        unsigned long long k0 = v0 ? (((unsigned long long)fsort(d0) << 32) | (unsigned)j0)
                                   : 0xFFFFFFFFFFFFFFFFULL;
        unsigned long long k1 = v1 ? (((unsigned long long)fsort(d1) << 32) | (unsigned)j1)
                                   : 0xFFFFFFFFFFFFFFFFULL;
        unsigned long long k = (k1 < k0) ? k1 : k0;
        #pragma unroll
        for (int off = 1; off < 64; off <<= 1) {
            unsigned long long o = __shfl_xor(k, off);
            if (o < k) k = o;
        }
        if (lane == 0) atomicMin(RES + r, k);
    }
}

// ---------- finalize: unpack RES -> out idx + rsum
__global__ void finalize_kernel(const unsigned long long* __restrict__ RES,
                                float* __restrict__ out, float* __restrict__ rsum) {
    int r = blockIdx.x * 256 + threadIdx.x;
    if (r >= NPATCH) return;
    unsigned long long v = RES[r];
    unsigned int j = (unsigned int)v;
    unsigned int u = (unsigned int)(v >> 32);
    unsigned int b = (u & 0x80000000u) ? (u ^ 0x80000000u) : ~u;
    out[1 + r] = (float)j;
    rsum[r] = __builtin_bit_cast(float, b);
}

// ---------- deterministic final loss
__global__ void loss_final(const float* __restrict__ rsum, float* __restrict__ out) {
    __shared__ float s[256];
    float acc = 0.f;
    for (int i = threadIdx.x; i < NPATCH; i += 256) acc += rsum[i];
    s[threadIdx.x] = acc;
    __syncthreads();
    for (int st = 128; st > 0; st >>= 1) {
        if (threadIdx.x < st) s[threadIdx.x] += s[threadIdx.x + st];
        __syncthreads();
    }
    if (threadIdx.x == 0) out[0] = s[0] / (float)NPATCH;
}

extern "C" void kernel_launch(void* const* d_in, const int* in_sizes, int n_in,
                              void* d_out, int out_size, void* d_ws, size_t ws_size,
                              hipStream_t stream) {
    const float* crop = (const float*)d_in[0];
    const float* orig = (const float*)d_in[1];
    float* out = (float*)d_out;

    unsigned short* Abig = (unsigned short*)d_ws;                    // 3.15 MB
    unsigned short* Bbig = Abig + (size_t)ATILES * TILE_SHORTS;      // 2.97 MB
    unsigned long long* RES = (unsigned long long*)(Bbig + (size_t)NT * TILE_SHORTS); // 123 KB
    float* PM = (float*)(RES + NPATCH);                              // 7.63 MB
    float* X2 = PM + (size_t)NPATCH * PMW;
    float* Y2 = X2 + NPATCH;
    float* RS = Y2 + NP;
    unsigned int* WL = (unsigned int*)(RS + NPATCH);                 // 7.44 MB (worst case)
    unsigned int* WLn = WL + (size_t)NPATCH * NT;

    sqnorm2<<<(NP + NPATCH + 255) / 256, 256, 0, stream>>>(crop, orig, X2, Y2, WLn);
    pack2<<<(ATILES + NT) * 6, 256, 0, stream>>>(crop, orig, Abig, Bbig, Y2);
    dist_mfma3<<<256, 512, 0, stream>>>(Abig, Bbig, PM);
    flag_kernel<<<NPATCH / 4, 256, 0, stream>>>(PM, WL, WLn, RES);
    repair_items<<<2048, 256, 0, stream>>>(crop, orig, X2, Y2, WL, WLn, RES);
    finalize_kernel<<<(NPATCH + 255) / 256, 256, 0, stream>>>(RES, out, RS);
    loss_final<<<1, 256, 0, stream>>>(RS, out);
}